// Round 5
// baseline (83.323 us; speedup 1.0000x reference)
//
#include <hip/hip_runtime.h>

#define B_SZ 16384
#define N_SP 129
#define GRID 512
#define BLOCK 256

typedef _Float16 half8 __attribute__((ext_vector_type(8)));
typedef float float4v __attribute__((ext_vector_type(4)));

#define WS_P1 0
#define WS_P2 512

// index into main_w for quadratic pair (i<j), N=129: N + i*(2N-i-1)/2 + (j-i-1)
__device__ __forceinline__ int qidx(int i, int j) {
  return N_SP + i * (2 * N_SP - i - 1) / 2 + (j - i - 1);
}

// tanh(x) = 1 - 2/(e^{2x}+1): monotone, stable both tails; fmin/fmax absorb NaN garbage
__device__ __forceinline__ float fast_tanh(float x) {
  float xc = fminf(fmaxf(x, -15.f), 15.f);
  float e = __expf(2.f * xc);
  return 1.f - 2.f / (e + 1.f);
}

// Fully fused: per-block gather of all coefficient tables (mw/tw are L2-hot
// broadcasts), then 4 waves x 8 rows of MFMA compute. 2 blocks/CU.
__global__ __launch_bounds__(BLOCK, 2) void main_kernel(
    const float* __restrict__ inps, const float* __restrict__ tw,
    const float* __restrict__ tb, const float* __restrict__ mw,
    float* __restrict__ out, float* __restrict__ wsf) {
  // B-frags: 24 frags x 64 lanes x 8 f16; frag = tbl*8 + t*4 + g
  __shared__ __align__(16) _Float16 s_frag[12288];
  // per-wave x / dt tiles: 16 rows x stride 72 f16 (rows 8..15 never written;
  // they only feed MFMA C-rows 8..15, which are never consumed)
  __shared__ __align__(16) _Float16 s_x[4 * 1152];
  __shared__ __align__(16) _Float16 s_dt[4 * 1152];
  __shared__ float s_small[324];  // twy|qxy|qyt|lint|tb (64 each) + liny
  __shared__ float s_red[8];

  const int tid = threadIdx.x;

  // ---- gather phase: build fragment tables in LDS (f16) ----
#pragma unroll 4
  for (int s = 0; s < 48; s++) {
    int idx = tid + BLOCK * s;      // 0..12287
    int frag = idx >> 9, e = idx & 511;
    int lane = e >> 3, j = e & 7;
    int tbl = frag >> 3, tg = frag & 7;
    int kt = tg >> 2, g = tg & 3;
    int k = kt * 32 + (lane >> 4) * 8 + j;   // K index (d or u), 0..63
    int n = (lane & 15) + 16 * g;            // N index (unit or i), 0..63
    float v;
    if (tbl == 0) {
      v = tw[n * 65 + k];                    // B[k][n] = tw[n][k]
    } else if (tbl == 1) {
      v = mw[qidx(n, 65 + k)];               // Qxt[i=n][u=k]
    } else {
      v = 0.f;
      if (n != k) {
        int a = n < k ? n : k, b = n < k ? k : n;
        v = mw[qidx(65 + a, 65 + b)];        // Qtt_sym
      }
    }
    s_frag[idx] = (_Float16)v;
  }
  if (tid < 64) {
    s_small[tid]       = tw[tid * 65 + 64];       // twy
    s_small[64 + tid]  = mw[qidx(tid, 64)];       // qxy
    s_small[128 + tid] = mw[qidx(64, 65 + tid)];  // qyt
    s_small[192 + tid] = mw[65 + tid];            // lint
    s_small[256 + tid] = tb[tid];
  }
  if (tid == 0) s_small[320] = mw[64];            // liny

  // ---- per-wave x staging (8 rows x 65 floats -> f16, stride 72) ----
  const int l = tid & 63, wib = tid >> 6;
  const int wave = (blockIdx.x << 2) + wib;  // 0..2047
  const int b0 = wave << 3;                  // 8 rows per wave
  _Float16* xw = s_x + wib * 1152;
  _Float16* dw = s_dt + wib * 1152;
  {
    const float4* src4 = (const float4*)(inps + b0 * 65);  // 130 float4, 16B aligned
#pragma unroll
    for (int it = 0; it < 2; it++) {
      float4 v = src4[l + 64 * it];
      const float* vp = (const float*)&v;
      int f0 = (l + 64 * it) * 4;
#pragma unroll
      for (int c = 0; c < 4; c++) {
        unsigned idx = f0 + c;
        unsigned row = idx / 65u, col = idx - row * 65u;
        xw[row * 72 + col] = (_Float16)vp[c];
      }
    }
    if (l < 2) {
      float4 v = src4[128 + l];
      const float* vp = (const float*)&v;
      int f0 = (128 + l) * 4;
#pragma unroll
      for (int c = 0; c < 4; c++) {
        unsigned idx = f0 + c;
        unsigned row = idx / 65u, col = idx - row * 65u;
        xw[row * 72 + col] = (_Float16)vp[c];
      }
    }
  }
  __syncthreads();

  // ---- compute phase ----
  const int q = l >> 4, m = l & 15;
  const bool act = (q < 2);   // rows q*4+r valid only for q<2 (8 rows/wave)

  float twyv[4], tbv[4], qxyv[4], qytv[4], lintv[4];
#pragma unroll
  for (int g = 0; g < 4; g++) {
    int u = m + 16 * g;
    twyv[g] = s_small[u];
    qxyv[g] = s_small[64 + u];
    qytv[g] = s_small[128 + u];
    lintv[g] = s_small[192 + u];
    tbv[g] = s_small[256 + u];
  }
  const float liny = s_small[320];
  const half8* fragv = (const half8*)s_frag;

  // A-frags of x: lane holds row m, k = t*32 + q*8 + j (16B-aligned b128)
  half8 ax[2];
#pragma unroll
  for (int t = 0; t < 2; t++)
    ax[t] = *(const half8*)(xw + m * 72 + t * 32 + q * 8);

  float4v acc[4];
#pragma unroll
  for (int g = 0; g < 4; g++) { acc[g][0] = 0.f; acc[g][1] = 0.f; acc[g][2] = 0.f; acc[g][3] = 0.f; }
#pragma unroll
  for (int g = 0; g < 4; g++)
#pragma unroll
    for (int t = 0; t < 2; t++)
      acc[g] = __builtin_amdgcn_mfma_f32_16x16x32_f16(ax[t], fragv[(t * 4 + g) * 64 + l], acc[g], 0, 0, 0);

  // epilogue 1: tanh pair, penalties, dt (f16) -> LDS for A-relayout
  float yv[4];
#pragma unroll
  for (int r = 0; r < 4; r++) yv[r] = (float)xw[(q * 4 + r) * 72 + 64];
  float dtv[4][4], stv[4][4];
  float pint = 0.f, pneut = 0.f;
#pragma unroll
  for (int g = 0; g < 4; g++)
#pragma unroll
    for (int r = 0; r < 4; r++) {
      float wpre = acc[g][r] + tbv[g];
      float w1 = wpre + twyv[g] * yv[r];
      float w2 = wpre - twyv[g] * yv[r];
      float t1 = fast_tanh(w1), t2 = fast_tanh(w2);
      float dt = t1 - t2, st = t1 + t2;
      dtv[g][r] = dt; stv[g][r] = st;
      if (act) {
        float a1 = 1.f - t1 * t1, a2 = 1.f - t2 * t2;
        pint += a1 * a1 + a2 * a2;
        float nv = t2 * w2 - t1 * w1;
        pneut += nv * nv;
        dw[(q * 4 + r) * 72 + m + 16 * g] = (_Float16)dt;
      }
    }

  // A-frags of dt (rows 8..15 garbage -> only unused C rows)
  half8 adt[2];
#pragma unroll
  for (int t = 0; t < 2; t++)
    adt[t] = *(const half8*)(dw + m * 72 + t * 32 + q * 8);

  float4v rxt[4], rtt[4];
#pragma unroll
  for (int g = 0; g < 4; g++) {
    rxt[g][0] = 0.f; rxt[g][1] = 0.f; rxt[g][2] = 0.f; rxt[g][3] = 0.f;
    rtt[g][0] = 0.f; rtt[g][1] = 0.f; rtt[g][2] = 0.f; rtt[g][3] = 0.f;
  }
#pragma unroll
  for (int g = 0; g < 4; g++)
#pragma unroll
    for (int t = 0; t < 2; t++) {
      rxt[g] = __builtin_amdgcn_mfma_f32_16x16x32_f16(adt[t], fragv[(8 + t * 4 + g) * 64 + l], rxt[g], 0, 0, 0);
      rtt[g] = __builtin_amdgcn_mfma_f32_16x16x32_f16(adt[t], fragv[(16 + t * 4 + g) * 64 + l], rtt[g], 0, 0, 0);
    }

  // final assembly: per (row=q*4+r, i=m+16g), reduce over g then lanes m
  float creg[4] = {0.f, 0.f, 0.f, 0.f};
#pragma unroll
  for (int g = 0; g < 4; g++)
#pragma unroll
    for (int r = 0; r < 4; r++) {
      float xv = (float)xw[(q * 4 + r) * 72 + m + 16 * g];
      creg[r] += xv * (2.f * yv[r] * qxyv[g] + rxt[g][r])
               + yv[r] * stv[g][r] * qytv[g]
               + 0.5f * stv[g][r] * rtt[g][r]
               + lintv[g] * dtv[g][r];
    }
#pragma unroll
  for (int r = 0; r < 4; r++) {
    float c = creg[r];
    c += __shfl_xor(c, 1); c += __shfl_xor(c, 2);
    c += __shfl_xor(c, 4); c += __shfl_xor(c, 8);
    if (act && m == 0) out[b0 + q * 4 + r] = 1.f + 2.f * yv[r] * liny + c;
  }

  // penalties: wave reduce (inactive lanes contribute 0) -> block -> ws partial
#pragma unroll
  for (int off = 1; off < 64; off <<= 1) {
    pint += __shfl_xor(pint, off);
    pneut += __shfl_xor(pneut, off);
  }
  if (l == 0) { s_red[wib] = pint; s_red[4 + wib] = pneut; }
  __syncthreads();
  if (tid == 0) {
    wsf[WS_P1 + blockIdx.x] = s_red[0] + s_red[1] + s_red[2] + s_red[3];
    wsf[WS_P2 + blockIdx.x] = s_red[4] + s_red[5] + s_red[6] + s_red[7];
  }
}

__global__ __launch_bounds__(512) void reduce_kernel(const float* __restrict__ wsf,
                                                     float* __restrict__ out) {
  __shared__ float s[16];
  const int tid = threadIdx.x;
  float a = wsf[WS_P1 + tid];
  float b = wsf[WS_P2 + tid];
#pragma unroll
  for (int off = 1; off < 64; off <<= 1) {
    a += __shfl_xor(a, off);
    b += __shfl_xor(b, off);
  }
  const int w = tid >> 6, l = tid & 63;
  if (l == 0) { s[w] = a; s[8 + w] = b; }
  __syncthreads();
  if (tid == 0) {
    float sa = 0.f, sb = 0.f;
#pragma unroll
    for (int i = 0; i < 8; i++) { sa += s[i]; sb += s[8 + i]; }
    out[B_SZ] = sa * (1.f / 300.f);
    out[B_SZ + 1] = sb;
  }
}

extern "C" void kernel_launch(void* const* d_in, const int* in_sizes, int n_in,
                              void* d_out, int out_size, void* d_ws, size_t ws_size,
                              hipStream_t stream) {
  const float* inps = (const float*)d_in[0];
  const float* tw   = (const float*)d_in[1];
  const float* tb   = (const float*)d_in[2];
  const float* mw   = (const float*)d_in[3];
  float* out = (float*)d_out;
  float* wsf = (float*)d_ws;
  main_kernel<<<GRID, BLOCK, 0, stream>>>(inps, tw, tb, mw, out, wsf);
  reduce_kernel<<<1, 512, 0, stream>>>(wsf, out);
}